// Round 3
// baseline (106.907 us; speedup 1.0000x reference)
//
#include <hip/hip_runtime.h>

// PlanarFlow: x = z + tanh(z@W0 + b0) @ W1 ; log_det = log|1 + (1-t^2)*(W0.W1)|
// z: [N,64] f32, W0: [64,1], b0: [1], W1: [1,64]
// d_out: x (N*64 floats) followed by log_det (N floats).
//
// Memory-bound (~516 MB traffic). 16 lanes per row, float4 per lane,
// shfl_xor butterfly within 16-lane groups for the row dot product.
// R3: unroll x2 (MLP=2) + non-temporal load/store via native clang
// ext_vector_type (HIP_vector_type rejected by the builtin).

typedef float f32x4 __attribute__((ext_vector_type(4)));

__global__ __launch_bounds__(256) void planar_flow_kernel(
    const float* __restrict__ z,
    const float* __restrict__ W0,
    const float* __restrict__ b0,
    const float* __restrict__ W1,
    float* __restrict__ x,
    float* __restrict__ log_det,
    int n_rows)
{
    const int tid    = blockIdx.x * blockDim.x + threadIdx.x;
    const int l      = threadIdx.x & 15;                    // lane within 16-group (column quad)
    const int g0     = tid >> 4;                            // starting row
    const int stride = (gridDim.x * blockDim.x) >> 4;       // rows per grid step

    const f32x4* __restrict__ z4 = reinterpret_cast<const f32x4*>(z);
    f32x4* __restrict__ x4       = reinterpret_cast<f32x4*>(x);

    // Per-thread W fragments (columns 4l..4l+3), loaded once (L1-resident).
    const f32x4 w0 = reinterpret_cast<const f32x4*>(W0)[l];
    const f32x4 w1 = reinterpret_cast<const f32x4*>(W1)[l];
    const float bias = b0[0];

    // s = W0 . W1 (scalar), reduced across the 16-lane group.
    float s = w0.x * w1.x + w0.y * w1.y + w0.z * w1.z + w0.w * w1.w;
    s += __shfl_xor(s, 1);
    s += __shfl_xor(s, 2);
    s += __shfl_xor(s, 4);
    s += __shfl_xor(s, 8);

    int row = g0;

    // Main loop: two independent rows in flight.
    for (; row + stride < n_rows; row += 2 * stride) {
        const int idx0 = row * 16 + l;
        const int idx1 = (row + stride) * 16 + l;

        const f32x4 zv0 = __builtin_nontemporal_load(z4 + idx0);
        const f32x4 zv1 = __builtin_nontemporal_load(z4 + idx1);

        float a0 = zv0.x * w0.x + zv0.y * w0.y + zv0.z * w0.z + zv0.w * w0.w;
        float a1 = zv1.x * w0.x + zv1.y * w0.y + zv1.z * w0.z + zv1.w * w0.w;
        a0 += __shfl_xor(a0, 1);  a1 += __shfl_xor(a1, 1);
        a0 += __shfl_xor(a0, 2);  a1 += __shfl_xor(a1, 2);
        a0 += __shfl_xor(a0, 4);  a1 += __shfl_xor(a1, 4);
        a0 += __shfl_xor(a0, 8);  a1 += __shfl_xor(a1, 8);
        a0 += bias;               a1 += bias;

        const float e0 = __expf(2.0f * a0);
        const float e1 = __expf(2.0f * a1);
        const float t0 = 1.0f - 2.0f / (e0 + 1.0f);
        const float t1 = 1.0f - 2.0f / (e1 + 1.0f);

        f32x4 xv0, xv1;
        xv0.x = fmaf(t0, w1.x, zv0.x);
        xv0.y = fmaf(t0, w1.y, zv0.y);
        xv0.z = fmaf(t0, w1.z, zv0.z);
        xv0.w = fmaf(t0, w1.w, zv0.w);
        xv1.x = fmaf(t1, w1.x, zv1.x);
        xv1.y = fmaf(t1, w1.y, zv1.y);
        xv1.z = fmaf(t1, w1.z, zv1.z);
        xv1.w = fmaf(t1, w1.w, zv1.w);
        __builtin_nontemporal_store(xv0, x4 + idx0);
        __builtin_nontemporal_store(xv1, x4 + idx1);

        if (l == 0) {
            const float det0 = fmaf(1.0f - t0 * t0, s, 1.0f);
            const float det1 = fmaf(1.0f - t1 * t1, s, 1.0f);
            __builtin_nontemporal_store(__logf(fabsf(det0)), log_det + row);
            __builtin_nontemporal_store(__logf(fabsf(det1)), log_det + row + stride);
        }
    }

    // Tail (at most one row per thread-group).
    for (; row < n_rows; row += stride) {
        const int idx = row * 16 + l;
        const f32x4 zv = __builtin_nontemporal_load(z4 + idx);

        float a = zv.x * w0.x + zv.y * w0.y + zv.z * w0.z + zv.w * w0.w;
        a += __shfl_xor(a, 1);
        a += __shfl_xor(a, 2);
        a += __shfl_xor(a, 4);
        a += __shfl_xor(a, 8);
        a += bias;

        const float e = __expf(2.0f * a);
        const float t = 1.0f - 2.0f / (e + 1.0f);

        f32x4 xv;
        xv.x = fmaf(t, w1.x, zv.x);
        xv.y = fmaf(t, w1.y, zv.y);
        xv.z = fmaf(t, w1.z, zv.z);
        xv.w = fmaf(t, w1.w, zv.w);
        __builtin_nontemporal_store(xv, x4 + idx);

        if (l == 0) {
            const float det = fmaf(1.0f - t * t, s, 1.0f);
            __builtin_nontemporal_store(__logf(fabsf(det)), log_det + row);
        }
    }
}

extern "C" void kernel_launch(void* const* d_in, const int* in_sizes, int n_in,
                              void* d_out, int out_size, void* d_ws, size_t ws_size,
                              hipStream_t stream) {
    const float* z  = (const float*)d_in[0];
    const float* W0 = (const float*)d_in[1];
    const float* b0 = (const float*)d_in[2];
    const float* W1 = (const float*)d_in[3];

    const int n_rows = in_sizes[0] / 64;          // 1048576
    float* x       = (float*)d_out;               // [N,64]
    float* log_det = x + (size_t)n_rows * 64;     // [N]

    const int block = 256;
    const int grid  = 4096;                       // grid-stride over rows
    planar_flow_kernel<<<grid, block, 0, stream>>>(z, W0, b0, W1, x, log_det, n_rows);
}